// Round 1
// baseline (235.930 us; speedup 1.0000x reference)
//
#include <hip/hip_runtime.h>

// YOLO 1D (audio) detection decoder, CENTER_DURATION encoding.
// Input  x: [B=32, G=131072, F=8] fp32 (8 floats / cell, 32B-aligned)
// Output   : fragments [B, G, 7] fp32, then mask [B, G] fp32 (1.0/0.0),
//            concatenated flat in d_out (tuple return order).
//
// Memory-bound: 128 MiB in + 128 MiB out, every byte touched exactly once.
//
// Key layout trick: 4 consecutive cells per thread -> the fragment record is
// 4 * 28 B = 112 B = 7 x float4, 16B-aligned (112 * t % 16 == 0). So fragments
// are stored as 7 direct global_store_dwordx4 per thread and the 4 mask values
// as one more dwordx4 -- NO LDS staging, NO barrier, ~3x fewer instructions
// per byte than the previous LDS-transpose version. Loads are 8 contiguous
// dwordx4 per thread (lane stride 128 B; the 8 back-to-back instructions cover
// the wave's 32 KB region densely, so L2 merges and HBM fetch stays exact).
//
// __fadd_rn/__fmul_rn block FMA contraction so rintf (round-nearest-even,
// = jnp.round) sees bit-identical pre-round values vs the JAX reference.
// halfd = x2 * 524288.0f is exact vs the reference's (x2*1048576)/2: both are
// pure power-of-two exponent shifts, no rounding in either path.

constexpr int BLOCK = 256;
constexpr int CPT   = 4;                 // consecutive cells per thread
constexpr int F_OUT = 7;

__global__ __launch_bounds__(BLOCK) void yolo_decode_kernel(
    const float4* __restrict__ in,       // [total_cells * 2] float4
    float4* __restrict__ frag4,          // [total_cells * 7 / 4] float4
    float4* __restrict__ mask4,          // [total_cells / 4] float4
    int g_mask,                          // G - 1 (G is a power of two)
    float cell_coef,                     // INPUT_LENGTH / G   (= 8.0f)
    float half_coef)                     // INPUT_LENGTH * 0.5 (= 524288.0f)
{
    const int t     = blockIdx.x * BLOCK + threadIdx.x;
    const int cell0 = t * CPT;

    // 4 cells = 8 contiguous float4 = 128 B per thread.
    float4 r[2 * CPT];
    const float4* p = in + (size_t)cell0 * 2;
    #pragma unroll
    for (int i = 0; i < 2 * CPT; ++i) r[i] = p[i];

    // cell0 % 4 == 0 and G % 4 == 0, so the 4 cells never wrap a batch row:
    // (cell0 + c) & g_mask == (cell0 & g_mask) + c.
    const int g0 = cell0 & g_mask;

    float v[CPT * F_OUT];
    float mk[CPT];

    #pragma unroll
    for (int c = 0; c < CPT; ++c) {
        const float4 a = r[2 * c];       // conf, x1 (center off), x2 (dur), x3
        const float4 b = r[2 * c + 1];   // x4, x5, x6, x7
        const bool  m  = a.x >= 0.5f;

        const float center = __fmul_rn(__fadd_rn((float)(g0 + c), a.y), cell_coef);
        const float halfd  = __fmul_rn(a.z, half_coef);          // exact pow2 scale
        const float s_val  = rintf(__fadd_rn(center, -halfd));   // v_rndne_f32
        const float e_val  = rintf(__fadd_rn(center,  halfd));

        v[c * F_OUT + 0] = m ? s_val : 0.0f;
        v[c * F_OUT + 1] = m ? e_val : 0.0f;
        v[c * F_OUT + 2] = m ? a.w   : 0.0f;
        v[c * F_OUT + 3] = m ? b.x   : 0.0f;
        v[c * F_OUT + 4] = m ? b.y   : 0.0f;
        v[c * F_OUT + 5] = m ? b.z   : 0.0f;
        v[c * F_OUT + 6] = m ? b.w   : 0.0f;
        mk[c] = m ? 1.0f : 0.0f;
    }

    // Fragments: 112 contiguous bytes per thread, 7 x dwordx4, 16B-aligned.
    float4* dst = frag4 + (size_t)t * F_OUT;
    #pragma unroll
    for (int k = 0; k < F_OUT; ++k)
        dst[k] = make_float4(v[4 * k + 0], v[4 * k + 1],
                             v[4 * k + 2], v[4 * k + 3]);

    // Mask: 4 consecutive floats per thread = 1 x dwordx4, 16B-aligned.
    mask4[t] = make_float4(mk[0], mk[1], mk[2], mk[3]);
}

extern "C" void kernel_launch(void* const* d_in, const int* in_sizes, int n_in,
                              void* d_out, int out_size, void* d_ws, size_t ws_size,
                              hipStream_t stream) {
    (void)n_in; (void)d_ws; (void)ws_size; (void)out_size;

    const float* x   = (const float*)d_in[0];
    float*       out = (float*)d_out;

    constexpr int F_IN        = 8;
    constexpr int G           = 131072;
    constexpr float INPUT_LEN = 1048576.0f;

    const int total_cells = in_sizes[0] / F_IN;          // 32 * 131072 = 4,194,304
    float* frag = out;                                   // [total_cells * 7]
    float* mask = out + (size_t)total_cells * F_OUT;     // [total_cells]
    // mask offset = total_cells*7*4 B = 117,440,512 B, 16B-aligned.

    const int blocks = total_cells / (BLOCK * CPT);      // exact: 4096 blocks

    yolo_decode_kernel<<<blocks, BLOCK, 0, stream>>>(
        (const float4*)x, (float4*)frag, (float4*)mask,
        G - 1, INPUT_LEN / (float)G, INPUT_LEN * 0.5f);
}

// Round 3
// 228.273 us; speedup vs baseline: 1.0335x; 1.0335x over previous
//
#include <hip/hip_runtime.h>

// YOLO 1D (audio) detection decoder, CENTER_DURATION encoding.
// Input  x: [B=32, G=131072, F=8] fp32 (8 floats / cell, 32B-aligned)
// Output   : fragments [B, G, 7] fp32, then mask [B, G] fp32 (1.0/0.0),
//            concatenated flat in d_out (tuple return order).
//
// Memory-bound: 128 MiB in + 128 MiB out. Lesson from round 1 (CPT=4,
// per-lane-contiguous 112B records, 86-89 us @ 28% HBM): per-lane-private
// 128B regions make every dwordx4 touch 64 distinct cache lines -> the
// kernel becomes VMEM-request-rate-limited, not BW-limited. So:
//
//  - 1 thread per cell; two stride-32B dwordx4 loads (16 lines/instr, 2x
//    amplification only — measured round 0/1: FETCH shows zero over-fetch,
//    L3 absorbs half the input re-read).
//  - ALL outputs staged in LDS (1792 frag dwords stride-7: 7 coprime 32 ->
//    2-way wave64 aliasing = free; +256 mask dwords stride-1).
//  - Write-back: exactly 512 float4 per block = 2 global_store_dwordx4 per
//    thread, perfectly lane-contiguous (8 lines/instr). Second sweep splits
//    at a wave boundary: waves 0-2 store frag, wave 3 stores mask — no
//    divergence within any wave. Stores are nontemporal so the 128 MiB
//    output stream doesn't evict the L3-resident input.
//
// NOTE: __builtin_nontemporal_store requires a NATIVE vector type — HIP's
// float4 (HIP_vector_type class) is rejected (round-2 compile failure).
// We use clang ext_vector_type(4) for all nontemporal paths.
//
// __fadd_rn/__fmul_rn block FMA contraction so rintf (round-nearest-even,
// = jnp.round) sees bit-identical pre-round values vs the JAX reference.
// halfd = x2 * 524288.0f is exact vs the reference's (x2*1048576)/2: both
// are pure power-of-two exponent scalings.

constexpr int BLOCK = 256;
constexpr int F_OUT = 7;

typedef float f32x4 __attribute__((ext_vector_type(4)));

__global__ __launch_bounds__(BLOCK) void yolo_decode_kernel(
    const f32x4* __restrict__ in,        // [total_cells * 2] float4
    f32x4* __restrict__ frag4,           // frag region as float4
    f32x4* __restrict__ mask4,           // mask region as float4
    int g_mask,                          // G - 1 (G is a power of two)
    float cell_coef,                     // INPUT_LENGTH / G   (= 8.0f)
    float half_coef)                     // INPUT_LENGTH * 0.5 (= 524288.0f)
{
    // 1792 frag dwords + 256 mask dwords = 2048 dwords = 8 KB.
    __shared__ float s[BLOCK * F_OUT + BLOCK];

    const int tid       = threadIdx.x;
    const int cell_base = blockIdx.x * BLOCK;
    const int cell      = cell_base + tid;

    // 32 B per cell: two dwordx4 loads, lane stride 32 B.
    const f32x4 a = in[(size_t)cell * 2];       // conf, x1 (center), x2 (dur), x3
    const f32x4 b = in[(size_t)cell * 2 + 1];   // x4, x5, x6, x7

    const int  g = cell & g_mask;               // grid-cell index within batch row
    const bool m = a.x >= 0.5f;

    const float center = __fmul_rn(__fadd_rn((float)g, a.y), cell_coef);
    const float halfd  = __fmul_rn(a.z, half_coef);          // exact pow2 scale
    const float s_val  = rintf(__fadd_rn(center, -halfd));   // v_rndne_f32 = jnp.round
    const float e_val  = rintf(__fadd_rn(center,  halfd));

    const float o[F_OUT] = { s_val, e_val, a.w, b.x, b.y, b.z, b.w };
    #pragma unroll
    for (int k = 0; k < F_OUT; ++k)
        s[tid * F_OUT + k] = m ? o[k] : 0.0f;    // stride-7: conflict-free
    s[BLOCK * F_OUT + tid] = m ? 1.0f : 0.0f;    // stride-1: conflict-free

    __syncthreads();

    // 512 float4 per block: 448 frag + 64 mask. Two coalesced sweeps.
    const f32x4* s4 = (const f32x4*)s;

    // Sweep 1: all 256 threads -> frag float4 [0..255] of this block.
    f32x4* fdst = frag4 + (size_t)cell_base * F_OUT / 4;     // 448 f4 per block
    __builtin_nontemporal_store(s4[tid], &fdst[tid]);

    // Sweep 2: waves 0-2 -> frag float4 [256..447]; wave 3 -> mask [0..63].
    if (tid < 192) {
        __builtin_nontemporal_store(s4[256 + tid], &fdst[256 + tid]);
    } else {
        f32x4* mdst = mask4 + (cell_base >> 2);              // 64 f4 per block
        __builtin_nontemporal_store(s4[448 + (tid - 192)], &mdst[tid - 192]);
    }
}

extern "C" void kernel_launch(void* const* d_in, const int* in_sizes, int n_in,
                              void* d_out, int out_size, void* d_ws, size_t ws_size,
                              hipStream_t stream) {
    (void)n_in; (void)d_ws; (void)ws_size; (void)out_size;

    const float* x   = (const float*)d_in[0];
    float*       out = (float*)d_out;

    constexpr int F_IN        = 8;
    constexpr int G           = 131072;
    constexpr float INPUT_LEN = 1048576.0f;

    const int total_cells = in_sizes[0] / F_IN;          // 32 * 131072 = 4,194,304
    float* frag = out;                                   // [total_cells * 7]
    float* mask = out + (size_t)total_cells * F_OUT;     // [total_cells]
    // mask byte offset = total_cells*7*4 = 117,440,512 — 16B-aligned.

    const int blocks = total_cells / BLOCK;              // exact: 16384 blocks

    yolo_decode_kernel<<<blocks, BLOCK, 0, stream>>>(
        (const f32x4*)x, (f32x4*)frag, (f32x4*)mask,
        G - 1, INPUT_LEN / (float)G, INPUT_LEN * 0.5f);
}